// Round 9
// baseline (349.536 us; speedup 1.0000x reference)
//
#include <hip/hip_runtime.h>
#include <hip/hip_bf16.h>
#include <stdint.h>

#define N_NODES 50000
#define N_EDGES 500000
#define R_REL 8
#define HID 128
#define KIN 128              // GEMM K (input features)
#define KOUT 1152            // 9*128: slabs W_0..W_7 | root
#define N8 400000            // N_NODES * R_REL composite buckets
#define NPAD 50048           // 3128 * 16
#define NUM_GRAPHS 64
#define NUM_CLASSES 16

typedef __attribute__((ext_vector_type(8))) short bf16x8;
typedef __attribute__((ext_vector_type(4))) float f32x4;

// ---------- helpers ----------
__device__ __forceinline__ uint16_t f2bf(float f) {
  uint32_t u = __float_as_uint(f);
  u += 0x7FFFu + ((u >> 16) & 1u);   // RNE
  return (uint16_t)(u >> 16);
}
__device__ __forceinline__ float bf2f(uint32_t b) {
  return __uint_as_float(b << 16);
}
__device__ __forceinline__ uint32_t pack2bf(float a, float b) {
  return (uint32_t)f2bf(a) | ((uint32_t)f2bf(b) << 16);
}

// ---------- merged prep: hist | bounds | prepw1 | prepw2 ----------
#define HIST_B 1954
#define BND_B 196
#define PW_B 576            // KOUT*KIN / 256
__global__ __launch_bounds__(256) void k_prep(const int* __restrict__ ei, const int* __restrict__ et,
                                              int* __restrict__ deg8,
                                              const int* __restrict__ batch,
                                              int* __restrict__ gs, int* __restrict__ ge,
                                              const float* __restrict__ W1, const float* __restrict__ root1,
                                              uint16_t* __restrict__ Wf1,
                                              const float* __restrict__ W2, const float* __restrict__ root2,
                                              uint16_t* __restrict__ Wf2) {
  int b = blockIdx.x;
  if (b < HIST_B) {                                 // edge histogram
    int i = b * 256 + threadIdx.x;
    if (i < N_EDGES) atomicAdd(&deg8[ei[N_EDGES + i] * R_REL + et[i]], 1);
    return;
  }
  b -= HIST_B;
  if (b < BND_B) {                                  // graph boundaries (batch sorted)
    int i = b * 256 + threadIdx.x;
    if (i < N_NODES) {
      int g = batch[i];
      if (i == 0) gs[g] = 0;
      else { int pg = batch[i - 1]; if (pg != g) { ge[pg] = i; gs[g] = i; } }
      if (i == N_NODES - 1) ge[g] = N_NODES;
    }
    return;
  }
  b -= BND_B;
  {
    // prepw: Wf in B-frag order. frag f=(s*8+nt)*4+kc holds 64 lanes x 16B,
    // lane L=(quad,l16): element Wcat[k = kc*32+quad*8+e][col = s*128+nt*16+l16]
    const float* W    = (b < PW_B) ? W1 : W2;
    const float* root = (b < PW_B) ? root1 : root2;
    uint16_t*    Wf   = (b < PW_B) ? Wf1 : Wf2;
    int idx = (b % PW_B) * 256 + threadIdx.x;       // over KOUT*KIN
    int e = idx & 7, L = (idx >> 3) & 63, f = idx >> 9;
    int quad = L >> 4, l16 = L & 15;
    int kc = f & 3, nt = (f >> 2) & 7, s = f >> 5;
    int k = kc * 32 + quad * 8 + e;
    int no = nt * 16 + l16;
    float v = (s < R_REL) ? W[((size_t)s * KIN + k) * HID + no] : root[(size_t)k * HID + no];
    Wf[idx] = f2bf(v);
  }
}

// ---------- scans ----------
__global__ __launch_bounds__(256) void k_scan1(const int* __restrict__ deg8, int* __restrict__ offs8,
                                               int* __restrict__ bsum) {
  __shared__ int sh[256];
  int t = threadIdx.x;
  int base = blockIdx.x * 1024 + t * 4;
  int v[4]; int s = 0;
  #pragma unroll
  for (int i = 0; i < 4; ++i) { int idx = base + i; v[i] = (idx < N8) ? deg8[idx] : 0; s += v[i]; }
  sh[t] = s;
  __syncthreads();
  for (int d = 1; d < 256; d <<= 1) {
    int add = (t >= d) ? sh[t - d] : 0;
    __syncthreads();
    sh[t] += add;
    __syncthreads();
  }
  int run = sh[t] - s;
  if (t == 255) bsum[blockIdx.x] = sh[255];
  #pragma unroll
  for (int i = 0; i < 4; ++i) { int idx = base + i; if (idx < N8) offs8[idx] = run; run += v[i]; }
}

__global__ __launch_bounds__(512) void k_scan2(int* __restrict__ bsum, int nb) {
  __shared__ int sh[512];
  int t = threadIdx.x;
  int v = (t < nb) ? bsum[t] : 0;
  sh[t] = v;
  __syncthreads();
  for (int d = 1; d < 512; d <<= 1) {
    int add = (t >= d) ? sh[t - d] : 0;
    __syncthreads();
    sh[t] += add;
    __syncthreads();
  }
  if (t < nb) bsum[t] = sh[t] - v;   // exclusive
}

__global__ __launch_bounds__(256) void k_scan3(int* __restrict__ offs8, int* __restrict__ nxt,
                                               const int* __restrict__ bsum) {
  int i = blockIdx.x * 256 + threadIdx.x;
  if (i < N8) {
    int o = offs8[i] + bsum[i >> 10];
    offs8[i] = o;
    nxt[i] = o;
  }
  if (i == 0) offs8[N8] = N_EDGES;
}

// scatter: place edge; emit fused meta: {src|rel<<16, bits(1/cnt)}
__global__ __launch_bounds__(256) void k_scatter(const int* __restrict__ ei, const int* __restrict__ et,
                                                 const int* __restrict__ deg8, int* __restrict__ nxt,
                                                 uint2* __restrict__ epw) {
  int i = blockIdx.x * 256 + threadIdx.x;
  if (i < N_EDGES) {
    int rel = et[i];
    int key = ei[N_EDGES + i] * R_REL + rel;
    int p = atomicAdd(&nxt[key], 1);
    uint2 v;
    v.x = (uint32_t)ei[i] | ((uint32_t)rel << 16);        // src < 2^16
    v.y = __float_as_uint(1.0f / (float)deg8[key]);       // mean weight (cnt >= 1)
    epw[p] = v;
  }
}

// ---------- Y = in @ Wcat^T, register-resident bf16 MFMA ----------
// One wave = 16 rows x 1 slab (128 cols). 28152 waves -> store-issue parallelism.
// Y word layout (pair-swizzle): word wi of a (row,slab) holds features (wi, wi+64),
// which are lane-local pairs (nt, nt+4) in MFMA C-layout -> packed dword stores.
// k_msg reads word L per lane: features (L, L+64).
template<bool IN_BF16>
__global__ __launch_bounds__(256) void k_gemmY(const void* __restrict__ in,
                                               const uint16_t* __restrict__ Wf,
                                               uint16_t* __restrict__ Y) {
  int t = threadIdx.x, w = t >> 6, L = t & 63;
  int quad = L >> 4, l16 = L & 15;
  int s = blockIdx.x;                      // slab 0..8
  int rowB = (blockIdx.y * 4 + w) * 16;    // 16-row group

  // A frags: af[kc], A[m=l16][k=kc*32+quad*8+e], zero-padded past N_NODES
  int row = rowB + l16;
  bool valid = row < N_NODES;
  bf16x8 af[4];
  #pragma unroll
  for (int kc = 0; kc < 4; ++kc) {
    if (IN_BF16) {
      uint4 v = {0u, 0u, 0u, 0u};
      if (valid) v = *(const uint4*)((const uint16_t*)in + (size_t)row * KIN + kc * 32 + quad * 8);
      union { uint4 u; bf16x8 b; } cv; cv.u = v;
      af[kc] = cv.b;
    } else {
      float4 a = {0.f,0.f,0.f,0.f}, c = {0.f,0.f,0.f,0.f};
      if (valid) {
        const float* p = (const float*)in + (size_t)row * KIN + kc * 32 + quad * 8;
        a = *(const float4*)p;
        c = *(const float4*)(p + 4);
      }
      bf16x8 r;
      r[0] = (short)f2bf(a.x); r[1] = (short)f2bf(a.y); r[2] = (short)f2bf(a.z); r[3] = (short)f2bf(a.w);
      r[4] = (short)f2bf(c.x); r[5] = (short)f2bf(c.y); r[6] = (short)f2bf(c.z); r[7] = (short)f2bf(c.w);
      af[kc] = r;
    }
  }

  f32x4 acc[8];
  #pragma unroll
  for (int nt = 0; nt < 8; ++nt) acc[nt] = (f32x4){0.f, 0.f, 0.f, 0.f};
  #pragma unroll
  for (int kc = 0; kc < 4; ++kc) {
    bf16x8 bfr[8];
    #pragma unroll
    for (int nt = 0; nt < 8; ++nt) {
      int f = (s * 8 + nt) * 4 + kc;
      bfr[nt] = *(const bf16x8*)(Wf + (size_t)f * 512 + L * 8);   // 16B/lane coalesced
    }
    #pragma unroll
    for (int nt = 0; nt < 8; ++nt)
      acc[nt] = __builtin_amdgcn_mfma_f32_16x16x32_bf16(af[kc], bfr[nt], acc[nt], 0, 0, 0);
  }
  // epilogue: pair (nt, nt+4) -> one dword; C/D layout col=lane&15, row=quad*4+reg
  #pragma unroll
  for (int ntp = 0; ntp < 4; ++ntp) {
    int wi = ntp * 16 + l16;                 // word index within slab-row
    #pragma unroll
    for (int rg = 0; rg < 4; ++rg) {
      int r = rowB + quad * 4 + rg;
      uint32_t word = pack2bf(acc[ntp][rg], acc[ntp + 4][rg]);
      *(uint32_t*)(Y + (size_t)r * KOUT + s * HID + wi * 2) = word;
    }
  }
}

// ---------- message pass: h = relu(Σ_e w_e * Y_rel[src] + Y_root[n] + b) ----------
// One wave per node; flat edge loop, 16 independent gathers in flight.
// Lane L handles feature pair (L, L+64) per the Y pair-swizzle.
template<bool OUT_BF16>
__global__ __launch_bounds__(256) void k_msg(const uint16_t* __restrict__ Y,
                                             const uint2* __restrict__ epw,
                                             const int* __restrict__ offs8,
                                             const float* __restrict__ bias,
                                             void* __restrict__ hout) {
  int n = (blockIdx.x * 256 + threadIdx.x) >> 6;
  n = __builtin_amdgcn_readfirstlane(n);
  int L = threadIdx.x & 63;
  if (n >= N_NODES) return;
  uint32_t rv = *(const uint32_t*)(Y + (size_t)n * KOUT + R_REL * HID + L * 2);   // root slab
  float ax = bf2f(rv & 0xFFFFu);   // feature L
  float ay = bf2f(rv >> 16);       // feature L+64
  int o0 = offs8[n * R_REL];
  int o8 = offs8[n * R_REL + R_REL];
  for (int g = o0; g < o8; g += 16) {
    int m = min(16, o8 - g);
    uint2 ev[16]; uint32_t vv[16];
    #pragma unroll
    for (int i = 0; i < 16; ++i) if (i < m) ev[i] = epw[g + i];
    #pragma unroll
    for (int i = 0; i < 16; ++i) if (i < m)
      vv[i] = *(const uint32_t*)(Y + (size_t)(ev[i].x & 0xFFFFu) * KOUT + (ev[i].x >> 16) * HID + L * 2);
    #pragma unroll
    for (int i = 0; i < 16; ++i) if (i < m) {
      float wv = __uint_as_float(ev[i].y);
      ax += bf2f(vv[i] & 0xFFFFu) * wv;
      ay += bf2f(vv[i] >> 16) * wv;
    }
  }
  ax = fmaxf(ax + bias[L], 0.f);
  ay = fmaxf(ay + bias[L + 64], 0.f);
  if (OUT_BF16) {
    uint16_t* hb = (uint16_t*)hout + (size_t)n * HID;
    hb[L] = f2bf(ax);
    hb[L + 64] = f2bf(ay);
  } else {
    float* hf = (float*)hout + (size_t)n * HID;
    hf[L] = ax;
    hf[L + 64] = ay;
  }
}

// ---------- pooling: 4 partial blocks per graph + tiny final ----------
__global__ __launch_bounds__(256) void k_poolpart(const float* __restrict__ h,
                                                  const int* __restrict__ gs, const int* __restrict__ ge,
                                                  float* __restrict__ psum) {
  __shared__ float red[HID];
  int g = blockIdx.x >> 2, p = blockIdx.x & 3;
  int c = threadIdx.x & 127, ph = threadIdx.x >> 7;
  int s = gs[g], e = ge[g];
  int len = e - s;
  int quarter = (len + 3) >> 2;
  int n0 = s + p * quarter;
  int n1 = min(n0 + quarter, e);
  float acc = 0.f;
  for (int n = n0 + ph; n < n1; n += 2) acc += h[(size_t)n * HID + c];
  if (ph == 1) red[c] = acc;
  __syncthreads();
  if (ph == 0 && n0 < n1) atomicAdd(&psum[g * HID + c], acc + red[c]);
}

__global__ __launch_bounds__(1024) void k_final(const float* __restrict__ psum,
                                                const int* __restrict__ gs, const int* __restrict__ ge,
                                                const float* __restrict__ linW, const float* __restrict__ linb,
                                                float* __restrict__ out) {
  int i = threadIdx.x;              // 64*16 = 1024
  int g = i >> 4, c = i & 15;
  float inv = 1.f / fmaxf((float)(ge[g] - gs[g]), 1.f);
  float s = 0.f;
  #pragma unroll 8
  for (int k = 0; k < HID; ++k) s += psum[g * HID + k] * linW[k * NUM_CLASSES + c];
  out[i] = s * inv + linb[c];
}

// ---------- launch ----------
extern "C" void kernel_launch(void* const* d_in, const int* in_sizes, int n_in,
                              void* d_out, int out_size, void* d_ws, size_t ws_size,
                              hipStream_t stream) {
  const float* x     = (const float*)d_in[0];
  const int*   ei    = (const int*)d_in[1];   // [2,E]: [0..E) src, [E..2E) dst
  const int*   et    = (const int*)d_in[2];
  const int*   batch = (const int*)d_in[3];
  const float* W1    = (const float*)d_in[4];
  const float* root1 = (const float*)d_in[5];
  const float* b1    = (const float*)d_in[6];
  const float* W2    = (const float*)d_in[7];
  const float* root2 = (const float*)d_in[8];
  const float* b2    = (const float*)d_in[9];
  const float* linW  = (const float*)d_in[10];
  const float* linb  = (const float*)d_in[11];
  float* out = (float*)d_out;

  char* ws = (char*)d_ws;
  size_t off = 0;
  auto alloc = [&](size_t bytes) -> char* {
    char* p = ws + off;
    off += (bytes + 255) & ~(size_t)255;
    return p;
  };
  // zero-region: deg8 | gb | psum (contiguous, one memset)
  int*      deg8  = (int*)alloc((size_t)N8 * 4);
  int*      gb    = (int*)alloc(2 * NUM_GRAPHS * 4);
  float*    psum  = (float*)alloc((size_t)NUM_GRAPHS * HID * 4);
  size_t zbytes = (size_t)N8 * 4 + 512 + (size_t)NUM_GRAPHS * HID * 4;
  int*      gs    = gb;
  int*      ge    = gb + NUM_GRAPHS;
  int*      offs8 = (int*)alloc((size_t)(N8 + 1) * 4);
  int*      nxt   = (int*)alloc((size_t)N8 * 4);
  int*      bsum  = (int*)alloc(512 * 4);
  uint2*    epw   = (uint2*)alloc((size_t)N_EDGES * 8);
  uint16_t* Wf1   = (uint16_t*)alloc((size_t)KOUT * KIN * 2);
  uint16_t* Wf2   = (uint16_t*)alloc((size_t)KOUT * KIN * 2);
  uint16_t* Y     = (uint16_t*)alloc((size_t)NPAD * KOUT * 2);   // 115 MB, reused both layers
  uint16_t* h1b   = (uint16_t*)alloc((size_t)N_NODES * HID * 2);
  float*    h2    = (float*)alloc((size_t)N_NODES * HID * 4);

  hipMemsetAsync(deg8, 0, zbytes, stream);

  int nb = (N8 + 1023) / 1024;          // 391 <= 512
  k_prep<<<HIST_B + BND_B + 2 * PW_B, 256, 0, stream>>>(
      ei, et, deg8, batch, gs, ge, W1, root1, Wf1, W2, root2, Wf2);
  k_scan1<<<nb, 256, 0, stream>>>(deg8, offs8, bsum);
  k_scan2<<<1, 512, 0, stream>>>(bsum, nb);
  k_scan3<<<(N8 + 255) / 256, 256, 0, stream>>>(offs8, nxt, bsum);
  k_scatter<<<(N_EDGES + 255) / 256, 256, 0, stream>>>(ei, et, deg8, nxt, epw);

  // layer 1
  k_gemmY<false><<<dim3(9, NPAD / 64), 256, 0, stream>>>(x, Wf1, Y);
  k_msg<true ><<<N_NODES / 4, 256, 0, stream>>>(Y, epw, offs8, b1, h1b);
  // layer 2
  k_gemmY<true ><<<dim3(9, NPAD / 64), 256, 0, stream>>>(h1b, Wf2, Y);
  k_msg<false><<<N_NODES / 4, 256, 0, stream>>>(Y, epw, offs8, b2, h2);

  k_poolpart<<<4 * NUM_GRAPHS, 256, 0, stream>>>(h2, gs, ge, psum);
  k_final<<<1, 1024, 0, stream>>>(psum, gs, ge, linW, linb, out);
}

// Round 10
// 329.212 us; speedup vs baseline: 1.0617x; 1.0617x over previous
//
#include <hip/hip_runtime.h>
#include <hip/hip_bf16.h>
#include <stdint.h>

#define N_NODES 50000
#define N_EDGES 500000
#define R_REL 8
#define HID 128
#define KIN 128              // GEMM K (input features)
#define KOUT 1152            // 9*128: slabs W_0..W_7 | root
#define N8 400000            // N_NODES * R_REL composite buckets
#define NPAD 50048           // 782 * 64
#define NUM_GRAPHS 64
#define NUM_CLASSES 16

typedef __attribute__((ext_vector_type(8))) short bf16x8;
typedef __attribute__((ext_vector_type(4))) float f32x4;

// ---------- helpers ----------
__device__ __forceinline__ uint16_t f2bf(float f) {
  uint32_t u = __float_as_uint(f);
  u += 0x7FFFu + ((u >> 16) & 1u);   // RNE
  return (uint16_t)(u >> 16);
}
__device__ __forceinline__ float bf2f(uint32_t b) {
  return __uint_as_float(b << 16);
}
__device__ __forceinline__ uint32_t pack2bf(float a, float b) {
  return (uint32_t)f2bf(a) | ((uint32_t)f2bf(b) << 16);
}

// ---------- merged prep: hist | bounds | prepw1 | prepw2 ----------
#define HIST_B 1954
#define BND_B 196
#define PW_B 576            // KOUT*KIN / 256
__global__ __launch_bounds__(256) void k_prep(const int* __restrict__ ei, const int* __restrict__ et,
                                              int* __restrict__ deg8,
                                              const int* __restrict__ batch,
                                              int* __restrict__ gs, int* __restrict__ ge,
                                              const float* __restrict__ W1, const float* __restrict__ root1,
                                              uint16_t* __restrict__ Wf1,
                                              const float* __restrict__ W2, const float* __restrict__ root2,
                                              uint16_t* __restrict__ Wf2) {
  int b = blockIdx.x;
  if (b < HIST_B) {                                 // edge histogram
    int i = b * 256 + threadIdx.x;
    if (i < N_EDGES) atomicAdd(&deg8[ei[N_EDGES + i] * R_REL + et[i]], 1);
    return;
  }
  b -= HIST_B;
  if (b < BND_B) {                                  // graph boundaries (batch sorted)
    int i = b * 256 + threadIdx.x;
    if (i < N_NODES) {
      int g = batch[i];
      if (i == 0) gs[g] = 0;
      else { int pg = batch[i - 1]; if (pg != g) { ge[pg] = i; gs[g] = i; } }
      if (i == N_NODES - 1) ge[g] = N_NODES;
    }
    return;
  }
  b -= BND_B;
  {
    // prepw: Wf in B-frag order. frag f=(s*8+nt)*4+kc holds 64 lanes x 16B,
    // lane L=(quad,l16): element Wcat[k = kc*32+quad*8+e][col = s*128+nt*16+l16]
    const float* W    = (b < PW_B) ? W1 : W2;
    const float* root = (b < PW_B) ? root1 : root2;
    uint16_t*    Wf   = (b < PW_B) ? Wf1 : Wf2;
    int idx = (b % PW_B) * 256 + threadIdx.x;       // over KOUT*KIN
    int e = idx & 7, L = (idx >> 3) & 63, f = idx >> 9;
    int quad = L >> 4, l16 = L & 15;
    int kc = f & 3, nt = (f >> 2) & 7, s = f >> 5;
    int k = kc * 32 + quad * 8 + e;
    int no = nt * 16 + l16;
    float v = (s < R_REL) ? W[((size_t)s * KIN + k) * HID + no] : root[(size_t)k * HID + no];
    Wf[idx] = f2bf(v);
  }
}

// ---------- scans ----------
__global__ __launch_bounds__(256) void k_scan1(const int* __restrict__ deg8, int* __restrict__ offs8,
                                               int* __restrict__ bsum) {
  __shared__ int sh[256];
  int t = threadIdx.x;
  int base = blockIdx.x * 1024 + t * 4;
  int v[4]; int s = 0;
  #pragma unroll
  for (int i = 0; i < 4; ++i) { int idx = base + i; v[i] = (idx < N8) ? deg8[idx] : 0; s += v[i]; }
  sh[t] = s;
  __syncthreads();
  for (int d = 1; d < 256; d <<= 1) {
    int add = (t >= d) ? sh[t - d] : 0;
    __syncthreads();
    sh[t] += add;
    __syncthreads();
  }
  int run = sh[t] - s;
  if (t == 255) bsum[blockIdx.x] = sh[255];
  #pragma unroll
  for (int i = 0; i < 4; ++i) { int idx = base + i; if (idx < N8) offs8[idx] = run; run += v[i]; }
}

__global__ __launch_bounds__(512) void k_scan2(int* __restrict__ bsum, int nb) {
  __shared__ int sh[512];
  int t = threadIdx.x;
  int v = (t < nb) ? bsum[t] : 0;
  sh[t] = v;
  __syncthreads();
  for (int d = 1; d < 512; d <<= 1) {
    int add = (t >= d) ? sh[t - d] : 0;
    __syncthreads();
    sh[t] += add;
    __syncthreads();
  }
  if (t < nb) bsum[t] = sh[t] - v;   // exclusive
}

__global__ __launch_bounds__(256) void k_scan3(int* __restrict__ offs8, int* __restrict__ nxt,
                                               const int* __restrict__ bsum) {
  int i = blockIdx.x * 256 + threadIdx.x;
  if (i < N8) {
    int o = offs8[i] + bsum[i >> 10];
    offs8[i] = o;
    nxt[i] = o;
  }
  if (i == 0) offs8[N8] = N_EDGES;
}

// scatter: place edge; emit fused meta: {src|rel<<16, bits(1/cnt)}
__global__ __launch_bounds__(256) void k_scatter(const int* __restrict__ ei, const int* __restrict__ et,
                                                 const int* __restrict__ deg8, int* __restrict__ nxt,
                                                 uint2* __restrict__ epw) {
  int i = blockIdx.x * 256 + threadIdx.x;
  if (i < N_EDGES) {
    int rel = et[i];
    int key = ei[N_EDGES + i] * R_REL + rel;
    int p = atomicAdd(&nxt[key], 1);
    uint2 v;
    v.x = (uint32_t)ei[i] | ((uint32_t)rel << 16);        // src < 2^16
    v.y = __float_as_uint(1.0f / (float)deg8[key]);       // mean weight (cnt >= 1)
    epw[p] = v;
  }
}

// ---------- Y = in @ Wcat^T, register-resident bf16 MFMA ----------
// One wave = 16 rows x ALL 9 slabs (serial): A-frags loaded ONCE (1x A traffic, R8's
// minimum) with 3128 waves (R9's store-issue parallelism). 256-thr blocks, no LDS.
// Y word layout (pair-swizzle): word wi of a (row,slab) holds features (wi, wi+64)
// = lane-local pair (nt, nt+4) in MFMA C-layout -> packed dword stores.
template<bool IN_BF16>
__global__ __launch_bounds__(256) void k_gemmY(const void* __restrict__ in,
                                               const uint16_t* __restrict__ Wf,
                                               uint16_t* __restrict__ Y) {
  int t = threadIdx.x, w = t >> 6, L = t & 63;
  int quad = L >> 4, l16 = L & 15;
  int rowB = (blockIdx.x * 4 + w) * 16;    // wave's 16-row group

  // A frags: af[kc], A[m=l16][k=kc*32+quad*8+e], zero-padded past N_NODES
  int row = rowB + l16;
  bool valid = row < N_NODES;
  bf16x8 af[4];
  #pragma unroll
  for (int kc = 0; kc < 4; ++kc) {
    if (IN_BF16) {
      uint4 v = {0u, 0u, 0u, 0u};
      if (valid) v = *(const uint4*)((const uint16_t*)in + (size_t)row * KIN + kc * 32 + quad * 8);
      union { uint4 u; bf16x8 b; } cv; cv.u = v;
      af[kc] = cv.b;
    } else {
      float4 a = {0.f,0.f,0.f,0.f}, c = {0.f,0.f,0.f,0.f};
      if (valid) {
        const float* p = (const float*)in + (size_t)row * KIN + kc * 32 + quad * 8;
        a = *(const float4*)p;
        c = *(const float4*)(p + 4);
      }
      bf16x8 r;
      r[0] = (short)f2bf(a.x); r[1] = (short)f2bf(a.y); r[2] = (short)f2bf(a.z); r[3] = (short)f2bf(a.w);
      r[4] = (short)f2bf(c.x); r[5] = (short)f2bf(c.y); r[6] = (short)f2bf(c.z); r[7] = (short)f2bf(c.w);
      af[kc] = r;
    }
  }

  #pragma unroll 1
  for (int s = 0; s < 9; ++s) {
    f32x4 acc[8];
    #pragma unroll
    for (int nt = 0; nt < 8; ++nt) acc[nt] = (f32x4){0.f, 0.f, 0.f, 0.f};
    #pragma unroll
    for (int kc = 0; kc < 4; ++kc) {
      bf16x8 bfr[8];
      #pragma unroll
      for (int nt = 0; nt < 8; ++nt) {
        int f = (s * 8 + nt) * 4 + kc;
        bfr[nt] = *(const bf16x8*)(Wf + (size_t)f * 512 + L * 8);   // 16B/lane, L2-hot
      }
      #pragma unroll
      for (int nt = 0; nt < 8; ++nt)
        acc[nt] = __builtin_amdgcn_mfma_f32_16x16x32_bf16(af[kc], bfr[nt], acc[nt], 0, 0, 0);
    }
    // epilogue slab s: pair (nt, nt+4) -> one dword; C/D layout col=lane&15, row=quad*4+reg
    #pragma unroll
    for (int ntp = 0; ntp < 4; ++ntp) {
      int wi = ntp * 16 + l16;                 // word index within slab-row
      #pragma unroll
      for (int rg = 0; rg < 4; ++rg) {
        int r = rowB + quad * 4 + rg;
        uint32_t word = pack2bf(acc[ntp][rg], acc[ntp + 4][rg]);
        *(uint32_t*)(Y + (size_t)r * KOUT + s * HID + wi * 2) = word;
      }
    }
  }
}

// ---------- message pass: h = relu(Σ_e w_e * Y_rel[src] + Y_root[n] + b) ----------
// One wave per node; flat edge loop, 16 independent gathers in flight.
// Lane L handles feature pair (L, L+64) per the Y pair-swizzle.
template<bool OUT_BF16>
__global__ __launch_bounds__(256) void k_msg(const uint16_t* __restrict__ Y,
                                             const uint2* __restrict__ epw,
                                             const int* __restrict__ offs8,
                                             const float* __restrict__ bias,
                                             void* __restrict__ hout) {
  int n = (blockIdx.x * 256 + threadIdx.x) >> 6;
  n = __builtin_amdgcn_readfirstlane(n);
  int L = threadIdx.x & 63;
  if (n >= N_NODES) return;
  uint32_t rv = *(const uint32_t*)(Y + (size_t)n * KOUT + R_REL * HID + L * 2);   // root slab
  float ax = bf2f(rv & 0xFFFFu);   // feature L
  float ay = bf2f(rv >> 16);       // feature L+64
  int o0 = offs8[n * R_REL];
  int o8 = offs8[n * R_REL + R_REL];
  for (int g = o0; g < o8; g += 16) {
    int m = min(16, o8 - g);
    uint2 ev[16]; uint32_t vv[16];
    #pragma unroll
    for (int i = 0; i < 16; ++i) if (i < m) ev[i] = epw[g + i];
    #pragma unroll
    for (int i = 0; i < 16; ++i) if (i < m)
      vv[i] = *(const uint32_t*)(Y + (size_t)(ev[i].x & 0xFFFFu) * KOUT + (ev[i].x >> 16) * HID + L * 2);
    #pragma unroll
    for (int i = 0; i < 16; ++i) if (i < m) {
      float wv = __uint_as_float(ev[i].y);
      ax += bf2f(vv[i] & 0xFFFFu) * wv;
      ay += bf2f(vv[i] >> 16) * wv;
    }
  }
  ax = fmaxf(ax + bias[L], 0.f);
  ay = fmaxf(ay + bias[L + 64], 0.f);
  if (OUT_BF16) {
    uint16_t* hb = (uint16_t*)hout + (size_t)n * HID;
    hb[L] = f2bf(ax);
    hb[L + 64] = f2bf(ay);
  } else {
    float* hf = (float*)hout + (size_t)n * HID;
    hf[L] = ax;
    hf[L + 64] = ay;
  }
}

// ---------- pooling: 4 partial blocks per graph + tiny final ----------
__global__ __launch_bounds__(256) void k_poolpart(const float* __restrict__ h,
                                                  const int* __restrict__ gs, const int* __restrict__ ge,
                                                  float* __restrict__ psum) {
  __shared__ float red[HID];
  int g = blockIdx.x >> 2, p = blockIdx.x & 3;
  int c = threadIdx.x & 127, ph = threadIdx.x >> 7;
  int s = gs[g], e = ge[g];
  int len = e - s;
  int quarter = (len + 3) >> 2;
  int n0 = s + p * quarter;
  int n1 = min(n0 + quarter, e);
  float acc = 0.f;
  for (int n = n0 + ph; n < n1; n += 2) acc += h[(size_t)n * HID + c];
  if (ph == 1) red[c] = acc;
  __syncthreads();
  if (ph == 0 && n0 < n1) atomicAdd(&psum[g * HID + c], acc + red[c]);
}

__global__ __launch_bounds__(1024) void k_final(const float* __restrict__ psum,
                                                const int* __restrict__ gs, const int* __restrict__ ge,
                                                const float* __restrict__ linW, const float* __restrict__ linb,
                                                float* __restrict__ out) {
  int i = threadIdx.x;              // 64*16 = 1024
  int g = i >> 4, c = i & 15;
  float inv = 1.f / fmaxf((float)(ge[g] - gs[g]), 1.f);
  float s = 0.f;
  #pragma unroll 8
  for (int k = 0; k < HID; ++k) s += psum[g * HID + k] * linW[k * NUM_CLASSES + c];
  out[i] = s * inv + linb[c];
}

// ---------- launch ----------
extern "C" void kernel_launch(void* const* d_in, const int* in_sizes, int n_in,
                              void* d_out, int out_size, void* d_ws, size_t ws_size,
                              hipStream_t stream) {
  const float* x     = (const float*)d_in[0];
  const int*   ei    = (const int*)d_in[1];   // [2,E]: [0..E) src, [E..2E) dst
  const int*   et    = (const int*)d_in[2];
  const int*   batch = (const int*)d_in[3];
  const float* W1    = (const float*)d_in[4];
  const float* root1 = (const float*)d_in[5];
  const float* b1    = (const float*)d_in[6];
  const float* W2    = (const float*)d_in[7];
  const float* root2 = (const float*)d_in[8];
  const float* b2    = (const float*)d_in[9];
  const float* linW  = (const float*)d_in[10];
  const float* linb  = (const float*)d_in[11];
  float* out = (float*)d_out;

  char* ws = (char*)d_ws;
  size_t off = 0;
  auto alloc = [&](size_t bytes) -> char* {
    char* p = ws + off;
    off += (bytes + 255) & ~(size_t)255;
    return p;
  };
  // zero-region: deg8 | gb | psum (contiguous, one memset)
  int*      deg8  = (int*)alloc((size_t)N8 * 4);
  int*      gb    = (int*)alloc(2 * NUM_GRAPHS * 4);
  float*    psum  = (float*)alloc((size_t)NUM_GRAPHS * HID * 4);
  size_t zbytes = (size_t)N8 * 4 + 512 + (size_t)NUM_GRAPHS * HID * 4;
  int*      gs    = gb;
  int*      ge    = gb + NUM_GRAPHS;
  int*      offs8 = (int*)alloc((size_t)(N8 + 1) * 4);
  int*      nxt   = (int*)alloc((size_t)N8 * 4);
  int*      bsum  = (int*)alloc(512 * 4);
  uint2*    epw   = (uint2*)alloc((size_t)N_EDGES * 8);
  uint16_t* Wf1   = (uint16_t*)alloc((size_t)KOUT * KIN * 2);
  uint16_t* Wf2   = (uint16_t*)alloc((size_t)KOUT * KIN * 2);
  uint16_t* Y     = (uint16_t*)alloc((size_t)NPAD * KOUT * 2);   // 115 MB, reused both layers
  uint16_t* h1b   = (uint16_t*)alloc((size_t)N_NODES * HID * 2);
  float*    h2    = (float*)alloc((size_t)N_NODES * HID * 4);

  hipMemsetAsync(deg8, 0, zbytes, stream);

  int nb = (N8 + 1023) / 1024;          // 391 <= 512
  k_prep<<<HIST_B + BND_B + 2 * PW_B, 256, 0, stream>>>(
      ei, et, deg8, batch, gs, ge, W1, root1, Wf1, W2, root2, Wf2);
  k_scan1<<<nb, 256, 0, stream>>>(deg8, offs8, bsum);
  k_scan2<<<1, 512, 0, stream>>>(bsum, nb);
  k_scan3<<<(N8 + 255) / 256, 256, 0, stream>>>(offs8, nxt, bsum);
  k_scatter<<<(N_EDGES + 255) / 256, 256, 0, stream>>>(ei, et, deg8, nxt, epw);

  // layer 1
  k_gemmY<false><<<NPAD / 64, 256, 0, stream>>>(x, Wf1, Y);
  k_msg<true ><<<N_NODES / 4, 256, 0, stream>>>(Y, epw, offs8, b1, h1b);
  // layer 2
  k_gemmY<true ><<<NPAD / 64, 256, 0, stream>>>(h1b, Wf2, Y);
  k_msg<false><<<N_NODES / 4, 256, 0, stream>>>(Y, epw, offs8, b2, h2);

  k_poolpart<<<4 * NUM_GRAPHS, 256, 0, stream>>>(h2, gs, ge, psum);
  k_final<<<1, 1024, 0, stream>>>(psum, gs, ge, linW, linb, out);
}

// Round 11
// 318.566 us; speedup vs baseline: 1.0972x; 1.0334x over previous
//
#include <hip/hip_runtime.h>
#include <hip/hip_bf16.h>
#include <stdint.h>

#define N_NODES 50000
#define N_EDGES 500000
#define R_REL 8
#define HID 128
#define KIN 128              // GEMM K (input features)
#define N8 400000            // N_NODES * R_REL composite buckets
#define NPAD 50048           // 782 * 64
#define NUM_GRAPHS 64
#define NUM_CLASSES 16
#define KOUT 1152            // 9*128 (Wf covers 8 msg slabs + root slab)

typedef __attribute__((ext_vector_type(8))) short bf16x8;
typedef __attribute__((ext_vector_type(4))) float f32x4;
typedef __attribute__((ext_vector_type(2))) float f32x2;

// ---------- helpers ----------
__device__ __forceinline__ uint16_t f2bf(float f) {
  uint32_t u = __float_as_uint(f);
  u += 0x7FFFu + ((u >> 16) & 1u);   // RNE
  return (uint16_t)(u >> 16);
}
__device__ __forceinline__ float bf2f(uint32_t b) {
  return __uint_as_float(b << 16);
}
__device__ __forceinline__ uint32_t pack2bf(float a, float b) {
  return (uint32_t)f2bf(a) | ((uint32_t)f2bf(b) << 16);
}

// ---------- merged prep: hist | bounds | prepw1 | prepw2 ----------
#define HIST_B 1954
#define BND_B 196
#define PW_B 576            // KOUT*KIN / 256
__global__ __launch_bounds__(256) void k_prep(const int* __restrict__ ei, const int* __restrict__ et,
                                              int* __restrict__ deg8,
                                              const int* __restrict__ batch,
                                              int* __restrict__ gs, int* __restrict__ ge,
                                              const float* __restrict__ W1, const float* __restrict__ root1,
                                              uint16_t* __restrict__ Wf1,
                                              const float* __restrict__ W2, const float* __restrict__ root2,
                                              uint16_t* __restrict__ Wf2) {
  int b = blockIdx.x;
  if (b < HIST_B) {                                 // edge histogram
    int i = b * 256 + threadIdx.x;
    if (i < N_EDGES) atomicAdd(&deg8[ei[N_EDGES + i] * R_REL + et[i]], 1);
    return;
  }
  b -= HIST_B;
  if (b < BND_B) {                                  // graph boundaries (batch sorted)
    int i = b * 256 + threadIdx.x;
    if (i < N_NODES) {
      int g = batch[i];
      if (i == 0) gs[g] = 0;
      else { int pg = batch[i - 1]; if (pg != g) { ge[pg] = i; gs[g] = i; } }
      if (i == N_NODES - 1) ge[g] = N_NODES;
    }
    return;
  }
  b -= BND_B;
  {
    // prepw: Wf in B-frag order. frag f=(s*8+nt)*4+kc holds 64 lanes x 16B,
    // lane L=(quad,l16): element Wcat[k = kc*32+quad*8+e][col = s*128+nt*16+l16]
    const float* W    = (b < PW_B) ? W1 : W2;
    const float* root = (b < PW_B) ? root1 : root2;
    uint16_t*    Wf   = (b < PW_B) ? Wf1 : Wf2;
    int idx = (b % PW_B) * 256 + threadIdx.x;       // over KOUT*KIN
    int e = idx & 7, L = (idx >> 3) & 63, f = idx >> 9;
    int quad = L >> 4, l16 = L & 15;
    int kc = f & 3, nt = (f >> 2) & 7, s = f >> 5;
    int k = kc * 32 + quad * 8 + e;
    int no = nt * 16 + l16;
    float v = (s < R_REL) ? W[((size_t)s * KIN + k) * HID + no] : root[(size_t)k * HID + no];
    Wf[idx] = f2bf(v);
  }
}

// ---------- scans ----------
__global__ __launch_bounds__(256) void k_scan1(const int* __restrict__ deg8, int* __restrict__ offs8,
                                               int* __restrict__ bsum) {
  __shared__ int sh[256];
  int t = threadIdx.x;
  int base = blockIdx.x * 1024 + t * 4;
  int v[4]; int s = 0;
  #pragma unroll
  for (int i = 0; i < 4; ++i) { int idx = base + i; v[i] = (idx < N8) ? deg8[idx] : 0; s += v[i]; }
  sh[t] = s;
  __syncthreads();
  for (int d = 1; d < 256; d <<= 1) {
    int add = (t >= d) ? sh[t - d] : 0;
    __syncthreads();
    sh[t] += add;
    __syncthreads();
  }
  int run = sh[t] - s;
  if (t == 255) bsum[blockIdx.x] = sh[255];
  #pragma unroll
  for (int i = 0; i < 4; ++i) { int idx = base + i; if (idx < N8) offs8[idx] = run; run += v[i]; }
}

__global__ __launch_bounds__(512) void k_scan2(int* __restrict__ bsum, int nb) {
  __shared__ int sh[512];
  int t = threadIdx.x;
  int v = (t < nb) ? bsum[t] : 0;
  sh[t] = v;
  __syncthreads();
  for (int d = 1; d < 512; d <<= 1) {
    int add = (t >= d) ? sh[t - d] : 0;
    __syncthreads();
    sh[t] += add;
    __syncthreads();
  }
  if (t < nb) bsum[t] = sh[t] - v;   // exclusive
}

__global__ __launch_bounds__(256) void k_scan3(int* __restrict__ offs8, int* __restrict__ nxt,
                                               const int* __restrict__ bsum) {
  int i = blockIdx.x * 256 + threadIdx.x;
  if (i < N8) {
    int o = offs8[i] + bsum[i >> 10];
    offs8[i] = o;
    nxt[i] = o;
  }
  if (i == 0) offs8[N8] = N_EDGES;
}

// scatter: place edge; emit fused meta: {src|rel<<16, bits(1/cnt)}
__global__ __launch_bounds__(256) void k_scatter(const int* __restrict__ ei, const int* __restrict__ et,
                                                 const int* __restrict__ deg8, int* __restrict__ nxt,
                                                 uint2* __restrict__ epw) {
  int i = blockIdx.x * 256 + threadIdx.x;
  if (i < N_EDGES) {
    int rel = et[i];
    int key = ei[N_EDGES + i] * R_REL + rel;
    int p = atomicAdd(&nxt[key], 1);
    uint2 v;
    v.x = (uint32_t)ei[i] | ((uint32_t)rel << 16);        // src < 2^16
    v.y = __float_as_uint(1.0f / (float)deg8[key]);       // mean weight (cnt >= 1)
    epw[p] = v;
  }
}

// ---------- Y = in @ Wcat^T, register-resident bf16 MFMA ----------
// One wave = 16 rows x all 9 slabs (A loaded once; 3128 waves).
// Message slabs (s<8) stored FP8 e4m3 (HW cvt, RNE+sat): Ymsg[(row*8+s)*128B],
// position p = l16*4+ntp holds fp8pair(feat (p&3)*16+(p>>2), +64) -> 8-B stores/lane.
// Root slab stored bf16: Yroot[row*128 ushorts], dword p = bf16pair(same mapping)
// -> 16-B stores/lane. Consumer (k_msg) uses the same position mapping.
template<bool IN_BF16>
__global__ __launch_bounds__(256) void k_gemmY(const void* __restrict__ in,
                                               const uint16_t* __restrict__ Wf,
                                               uint8_t* __restrict__ Ymsg,
                                               uint16_t* __restrict__ Yroot) {
  int t = threadIdx.x, w = t >> 6, L = t & 63;
  int quad = L >> 4, l16 = L & 15;
  int rowB = (blockIdx.x * 4 + w) * 16;    // wave's 16-row group

  // A frags: af[kc], A[m=l16][k=kc*32+quad*8+e], zero-padded past N_NODES
  int row = rowB + l16;
  bool valid = row < N_NODES;
  bf16x8 af[4];
  #pragma unroll
  for (int kc = 0; kc < 4; ++kc) {
    if (IN_BF16) {
      uint4 v = {0u, 0u, 0u, 0u};
      if (valid) v = *(const uint4*)((const uint16_t*)in + (size_t)row * KIN + kc * 32 + quad * 8);
      union { uint4 u; bf16x8 b; } cv; cv.u = v;
      af[kc] = cv.b;
    } else {
      float4 a = {0.f,0.f,0.f,0.f}, c = {0.f,0.f,0.f,0.f};
      if (valid) {
        const float* p = (const float*)in + (size_t)row * KIN + kc * 32 + quad * 8;
        a = *(const float4*)p;
        c = *(const float4*)(p + 4);
      }
      bf16x8 r;
      r[0] = (short)f2bf(a.x); r[1] = (short)f2bf(a.y); r[2] = (short)f2bf(a.z); r[3] = (short)f2bf(a.w);
      r[4] = (short)f2bf(c.x); r[5] = (short)f2bf(c.y); r[6] = (short)f2bf(c.z); r[7] = (short)f2bf(c.w);
      af[kc] = r;
    }
  }

  #pragma unroll 1
  for (int s = 0; s < 9; ++s) {
    f32x4 acc[8];
    #pragma unroll
    for (int nt = 0; nt < 8; ++nt) acc[nt] = (f32x4){0.f, 0.f, 0.f, 0.f};
    #pragma unroll
    for (int kc = 0; kc < 4; ++kc) {
      bf16x8 bfr[8];
      #pragma unroll
      for (int nt = 0; nt < 8; ++nt) {
        int f = (s * 8 + nt) * 4 + kc;
        bfr[nt] = *(const bf16x8*)(Wf + (size_t)f * 512 + L * 8);   // 16B/lane, L2-hot
      }
      #pragma unroll
      for (int nt = 0; nt < 8; ++nt)
        acc[nt] = __builtin_amdgcn_mfma_f32_16x16x32_bf16(af[kc], bfr[nt], acc[nt], 0, 0, 0);
    }
    // epilogue: C/D layout col=nt*16+l16, row=quad*4+rg; pairs (nt, nt+4) lane-local
    if (s < 8) {
      #pragma unroll
      for (int rg = 0; rg < 4; ++rg) {
        int r = rowB + quad * 4 + rg;
        uint32_t d0 = (uint32_t)__builtin_amdgcn_cvt_pk_fp8_f32(acc[0][rg], acc[4][rg], 0, false);
        d0 = (uint32_t)__builtin_amdgcn_cvt_pk_fp8_f32(acc[1][rg], acc[5][rg], (int)d0, true);
        uint32_t d1 = (uint32_t)__builtin_amdgcn_cvt_pk_fp8_f32(acc[2][rg], acc[6][rg], 0, false);
        d1 = (uint32_t)__builtin_amdgcn_cvt_pk_fp8_f32(acc[3][rg], acc[7][rg], (int)d1, true);
        uint2 v = {d0, d1};
        *(uint2*)(Ymsg + ((size_t)r * R_REL + s) * 128 + l16 * 8) = v;
      }
    } else {
      #pragma unroll
      for (int rg = 0; rg < 4; ++rg) {
        int r = rowB + quad * 4 + rg;
        uint4 v;
        v.x = pack2bf(acc[0][rg], acc[4][rg]);
        v.y = pack2bf(acc[1][rg], acc[5][rg]);
        v.z = pack2bf(acc[2][rg], acc[6][rg]);
        v.w = pack2bf(acc[3][rg], acc[7][rg]);
        *(uint4*)(Yroot + (size_t)r * HID + l16 * 8) = v;
      }
    }
  }
}

// ---------- message pass: h = relu(Σ_e w_e * Ymsg[src,rel] + Yroot[n] + b) ----------
// One wave per node; flat edge loop, 16 independent fp8 gathers (128 B/wave each).
// Lane L reads position L -> features (fL, fL+64), fL = (L&3)*16 + (L>>2).
template<bool OUT_BF16>
__global__ __launch_bounds__(256) void k_msg(const uint8_t* __restrict__ Ymsg,
                                             const uint16_t* __restrict__ Yroot,
                                             const uint2* __restrict__ epw,
                                             const int* __restrict__ offs8,
                                             const float* __restrict__ bias,
                                             void* __restrict__ hout) {
  int n = (blockIdx.x * 256 + threadIdx.x) >> 6;
  n = __builtin_amdgcn_readfirstlane(n);
  int L = threadIdx.x & 63;
  if (n >= N_NODES) return;
  int fL = (L & 3) * 16 + (L >> 2);
  uint32_t rv = *(const uint32_t*)(Yroot + (size_t)n * HID + L * 2);   // root term (bf16 pair)
  float ax = bf2f(rv & 0xFFFFu);   // feature fL
  float ay = bf2f(rv >> 16);       // feature fL+64
  int o0 = offs8[n * R_REL];
  int o8 = offs8[n * R_REL + R_REL];
  for (int g = o0; g < o8; g += 16) {
    int m = min(16, o8 - g);
    uint2 ev[16]; uint32_t vv[16];
    #pragma unroll
    for (int i = 0; i < 16; ++i) if (i < m) ev[i] = epw[g + i];
    #pragma unroll
    for (int i = 0; i < 16; ++i) if (i < m)
      vv[i] = *(const uint16_t*)(Ymsg + ((size_t)(ev[i].x & 0xFFFFu) * R_REL + (ev[i].x >> 16)) * 128 + L * 2);
    #pragma unroll
    for (int i = 0; i < 16; ++i) if (i < m) {
      f32x2 f = __builtin_amdgcn_cvt_pk_f32_fp8((int)vv[i], false);
      float wv = __uint_as_float(ev[i].y);
      ax += f[0] * wv;
      ay += f[1] * wv;
    }
  }
  ax = fmaxf(ax + bias[fL], 0.f);
  ay = fmaxf(ay + bias[fL + 64], 0.f);
  if (OUT_BF16) {
    uint16_t* hb = (uint16_t*)hout + (size_t)n * HID;
    hb[fL] = f2bf(ax);
    hb[fL + 64] = f2bf(ay);
  } else {
    float* hf = (float*)hout + (size_t)n * HID;
    hf[fL] = ax;
    hf[fL + 64] = ay;
  }
}

// ---------- pooling: 4 partial blocks per graph + tiny final ----------
__global__ __launch_bounds__(256) void k_poolpart(const float* __restrict__ h,
                                                  const int* __restrict__ gs, const int* __restrict__ ge,
                                                  float* __restrict__ psum) {
  __shared__ float red[HID];
  int g = blockIdx.x >> 2, p = blockIdx.x & 3;
  int c = threadIdx.x & 127, ph = threadIdx.x >> 7;
  int s = gs[g], e = ge[g];
  int len = e - s;
  int quarter = (len + 3) >> 2;
  int n0 = s + p * quarter;
  int n1 = min(n0 + quarter, e);
  float acc = 0.f;
  for (int n = n0 + ph; n < n1; n += 2) acc += h[(size_t)n * HID + c];
  if (ph == 1) red[c] = acc;
  __syncthreads();
  if (ph == 0 && n0 < n1) atomicAdd(&psum[g * HID + c], acc + red[c]);
}

__global__ __launch_bounds__(1024) void k_final(const float* __restrict__ psum,
                                                const int* __restrict__ gs, const int* __restrict__ ge,
                                                const float* __restrict__ linW, const float* __restrict__ linb,
                                                float* __restrict__ out) {
  int i = threadIdx.x;              // 64*16 = 1024
  int g = i >> 4, c = i & 15;
  float inv = 1.f / fmaxf((float)(ge[g] - gs[g]), 1.f);
  float s = 0.f;
  #pragma unroll 8
  for (int k = 0; k < HID; ++k) s += psum[g * HID + k] * linW[k * NUM_CLASSES + c];
  out[i] = s * inv + linb[c];
}

// ---------- launch ----------
extern "C" void kernel_launch(void* const* d_in, const int* in_sizes, int n_in,
                              void* d_out, int out_size, void* d_ws, size_t ws_size,
                              hipStream_t stream) {
  const float* x     = (const float*)d_in[0];
  const int*   ei    = (const int*)d_in[1];   // [2,E]: [0..E) src, [E..2E) dst
  const int*   et    = (const int*)d_in[2];
  const int*   batch = (const int*)d_in[3];
  const float* W1    = (const float*)d_in[4];
  const float* root1 = (const float*)d_in[5];
  const float* b1    = (const float*)d_in[6];
  const float* W2    = (const float*)d_in[7];
  const float* root2 = (const float*)d_in[8];
  const float* b2    = (const float*)d_in[9];
  const float* linW  = (const float*)d_in[10];
  const float* linb  = (const float*)d_in[11];
  float* out = (float*)d_out;

  char* ws = (char*)d_ws;
  size_t off = 0;
  auto alloc = [&](size_t bytes) -> char* {
    char* p = ws + off;
    off += (bytes + 255) & ~(size_t)255;
    return p;
  };
  // zero-region: deg8 | gb | psum (contiguous, one memset)
  int*      deg8  = (int*)alloc((size_t)N8 * 4);
  int*      gb    = (int*)alloc(2 * NUM_GRAPHS * 4);
  float*    psum  = (float*)alloc((size_t)NUM_GRAPHS * HID * 4);
  size_t zbytes = (size_t)N8 * 4 + 512 + (size_t)NUM_GRAPHS * HID * 4;
  int*      gs    = gb;
  int*      ge    = gb + NUM_GRAPHS;
  int*      offs8 = (int*)alloc((size_t)(N8 + 1) * 4);
  int*      nxt   = (int*)alloc((size_t)N8 * 4);
  int*      bsum  = (int*)alloc(512 * 4);
  uint2*    epw   = (uint2*)alloc((size_t)N_EDGES * 8);
  uint16_t* Wf1   = (uint16_t*)alloc((size_t)KOUT * KIN * 2);
  uint16_t* Wf2   = (uint16_t*)alloc((size_t)KOUT * KIN * 2);
  uint8_t*  Ymsg  = (uint8_t*)alloc((size_t)NPAD * R_REL * 128);   // 51.2 MB fp8
  uint16_t* Yroot = (uint16_t*)alloc((size_t)NPAD * HID * 2);      // 12.8 MB bf16
  uint16_t* h1b   = (uint16_t*)alloc((size_t)N_NODES * HID * 2);
  float*    h2    = (float*)alloc((size_t)N_NODES * HID * 4);

  hipMemsetAsync(deg8, 0, zbytes, stream);

  int nb = (N8 + 1023) / 1024;          // 391 <= 512
  k_prep<<<HIST_B + BND_B + 2 * PW_B, 256, 0, stream>>>(
      ei, et, deg8, batch, gs, ge, W1, root1, Wf1, W2, root2, Wf2);
  k_scan1<<<nb, 256, 0, stream>>>(deg8, offs8, bsum);
  k_scan2<<<1, 512, 0, stream>>>(bsum, nb);
  k_scan3<<<(N8 + 255) / 256, 256, 0, stream>>>(offs8, nxt, bsum);
  k_scatter<<<(N_EDGES + 255) / 256, 256, 0, stream>>>(ei, et, deg8, nxt, epw);

  // layer 1
  k_gemmY<false><<<NPAD / 64, 256, 0, stream>>>(x, Wf1, Ymsg, Yroot);
  k_msg<true ><<<N_NODES / 4, 256, 0, stream>>>(Ymsg, Yroot, epw, offs8, b1, h1b);
  // layer 2
  k_gemmY<true ><<<NPAD / 64, 256, 0, stream>>>(h1b, Wf2, Ymsg, Yroot);
  k_msg<false><<<N_NODES / 4, 256, 0, stream>>>(Ymsg, Yroot, epw, offs8, b2, h2);

  k_poolpart<<<4 * NUM_GRAPHS, 256, 0, stream>>>(h2, gs, ge, psum);
  k_final<<<1, 1024, 0, stream>>>(psum, gs, ge, linW, linb, out);
}